// Round 20
// baseline (916.925 us; speedup 1.0000x reference)
//
#include <hip/hip_runtime.h>
#include <math.h>
#include <stdint.h>

#define BATCH 16
#define NCLS 80
#define SUMHW 7581            // 76*76 + 38*38 + 19*19
#define NN 22743              // 3 anchors * SUMHW
#define ASTRIDE 7584          // padded per-anchor stride for so/xthr (7581 -> 7584, /4)
#define PADNN (3 * ASTRIDE)   // 22752
#define TOPK 128
#define CAP 1024              // fallback gather cap
#define GCAP 2048             // per-(b,c) global list cap (mean ~670)
#define PRUNECAP 512          // post-prune survivor cap
#define KEYBASE 0x3E800000u   // bits of 0.25f (fallback histogram base)
#define KB2     0x3F180000u   // bits of 0.59375f (prune histogram base)
#define SBITS   0x3F19999Au   // bits of 0.6f

#define Q0 5891520            // p0 float4 quads: 16*255*(5776/4)
#define Q1 1472880            // p1 float4 quads: 16*255*(1444/4)
#define E2 1472880            // p2 scalar elems: 16*255*361
#define TOTW (Q0 + Q1 + E2)   // 8,837,280

typedef float f32x4 __attribute__((ext_vector_type(4)));

// exact sigmoid matching numpy f32 chain: correctly-rounded exp (double) -> f32 ops
__device__ __forceinline__ float sigf(float x) {
    float e = (float)exp(-(double)x);
    return 1.0f / (1.0f + e);
}
__device__ __forceinline__ float expf_cr(float x) {
    return (float)exp((double)x);
}

struct DecParams { float aw[9]; float ah[9]; };

// ---------------- Stage A: exact objectness + x-threshold (obj channel only) ----------
// xthr correctness (r5-r19 validated):
//   Tp = 0.59999 (< 0.6f).  thr = -log(so/Tp - 1)  =>  sigmoid(thr) = Tp/so.
//   ex >= 0.6f  =>  x > thr (captured).   x <= thr  =>  ex < 0.6f (safe to miss).
//   so <= 0.59999f  =>  ex < 0.6f  =>  xthr=+INF.
__global__ __launch_bounds__(256) void decode_kernel(
        const float* __restrict__ p0, const float* __restrict__ p1,
        const float* __restrict__ p2,
        float* __restrict__ so_arr, float* __restrict__ xthr_arr) {
    int blk = blockIdx.x;              // 16 b * 3 a * 9 segs = 432
    int b = blk / 27;
    int rem = blk % 27;
    int a = rem / 9;
    int seg = rem % 9;
    int s, segi;
    if (seg < 6)      { s = 0; segi = seg; }
    else if (seg < 8) { s = 1; segi = seg - 6; }
    else              { s = 2; segi = 0; }
    const int HW_[3]  = {5776, 1444, 361};
    const int OFF_[3] = {0, 5776, 7220};
    const float* __restrict__ pr = (s == 0) ? p0 : (s == 1) ? p1 : p2;
    int HW = HW_[s], OFF = OFF_[s];
    int t = threadIdx.x;

    auto mkthr = [](float so) {
        float thr = __int_as_float(0x7F800000);       // +INF
        if (so > 0.59999f) {
            double arg = (double)so / 0.59999 - 1.0;
            thr = __double2float_rd(-log(arg));       // round DOWN: conservative capture
        }
        return thr;
    };

    if (s != 2) {
        int cell0 = segi * 1024 + t * 4;
        if (cell0 >= HW) return;                      // active threads are full float4s
        const float4* ob4 =
            (const float4*)(pr + ((size_t)b * 255 + (size_t)a * 85 + 4) * (size_t)HW);
        float4 ov = ob4[cell0 >> 2];
        float4 sov, thv;
        sov.x = sigf(ov.x); thv.x = mkthr(sov.x);
        sov.y = sigf(ov.y); thv.y = mkthr(sov.y);
        sov.z = sigf(ov.z); thv.z = mkthr(sov.z);
        sov.w = sigf(ov.w); thv.w = mkthr(sov.w);
        size_t pidx = (size_t)b * PADNN + a * ASTRIDE + OFF + cell0;
        *(float4*)(so_arr + pidx)   = sov;
        *(float4*)(xthr_arr + pidx) = thv;
    } else {
        const float* ob = pr + ((size_t)b * 255 + (size_t)a * 85 + 4) * 361;
        for (int i = t; i < 361; i += 256) {
            float so = sigf(ob[i]);
            size_t pidx = (size_t)b * PADNN + a * ASTRIDE + 7220 + i;
            so_arr[pidx] = so;
            xthr_arr[pidx] = mkthr(so);
        }
    }
}

// ------- Stage B1: FLAT memcpy-shaped scan. One thread = one float4 of the raw
//         input, grid in flat address order => perfectly sequential HBM streams.
//         thr4 from 1.4MB L2-resident table. Survivors -> per-(b,c) global lists. ----
__global__ __launch_bounds__(256) void flat_scan_kernel(
        const float* __restrict__ p0, const float* __restrict__ p1,
        const float* __restrict__ p2,
        const float* __restrict__ xthr_arr,
        unsigned long long* __restrict__ glist, unsigned int* __restrict__ gcnt) {
    int gid = blockIdx.x * 256 + threadIdx.x;
    if (gid >= TOTW) return;

    const float* pr;
    int qpc, OFF, idx;
    if (gid < Q0)           { pr = p0; qpc = 1444; OFF = 0;    idx = gid; }
    else if (gid < Q0 + Q1) { pr = p1; qpc = 361;  OFF = 5776; idx = gid - Q0; }
    else {
        // ---- p2 scalar path (channel length 361 not /4) ----
        int e = gid - Q0 - Q1;
        int chan = e / 361;                  // magic-mul
        int cell = e - chan * 361;
        int b = chan / 255;
        int ch = chan - b * 255;
        int a = ch / 85;
        int chc = ch - a * 85;
        if (chc < 5) return;                 // box/obj channels
        float xv = p2[(size_t)gid - Q0 - Q1 + 0 ? 0 : 0];  // placeholder (not used)
        xv = p2[(size_t)e];                  // flat address == e
        size_t pi = (size_t)b * PADNN + a * ASTRIDE + 7220 + cell;
        if (xv > xthr_arr[pi]) {
            int bc = b * NCLS + (chc - 5);
            unsigned gp = atomicAdd(&gcnt[bc], 1u);
            if (gp < GCAP) glist[(size_t)bc * GCAP + gp] =
                (((unsigned long long)__float_as_uint(xv)) << 32) |
                (unsigned)(a * SUMHW + 7220 + cell);
        }
        return;
    }
    // ---- quad path (p0 / p1) ----
    int chan = idx / qpc;                    // magic-mul (qpc is compile-time per branch)
    int qc   = idx - chan * qpc;
    int b  = chan / 255;
    int ch = chan - b * 255;
    int a  = ch / 85;
    int chc = ch - a * 85;
    if (chc < 5) return;                     // box/obj channels (wave-uniform mostly)
    f32x4 xv = *(const f32x4*)(pr + (size_t)idx * 4);          // flat, linear
    const f32x4 tv = *(const f32x4*)(xthr_arr + (size_t)b * PADNN + a * ASTRIDE
                                     + OFF + 4 * (size_t)qc);  // L2-hot
    unsigned m = 0;
    m |= (xv.x > tv.x) ? 1u : 0u;
    m |= (xv.y > tv.y) ? 2u : 0u;
    m |= (xv.z > tv.z) ? 4u : 0u;
    m |= (xv.w > tv.w) ? 8u : 0u;
    if (m) {
        int bc = b * NCLS + (chc - 5);
        int n0 = a * SUMHW + OFF + 4 * qc;
        unsigned pos = atomicAdd(&gcnt[bc], (unsigned)__popc(m));
        unsigned long long* gl = glist + (size_t)bc * GCAP;
#define PKG(bit, val, nn) \
        if (m & (bit)) { if (pos < GCAP) gl[pos] = \
            (((unsigned long long)__float_as_uint(val)) << 32) | (unsigned)(nn); \
            pos++; }
        PKG(1u, xv.x, n0 + 0)
        PKG(2u, xv.y, n0 + 1)
        PKG(4u, xv.z, n0 + 2)
        PKG(8u, xv.w, n0 + 3)
#undef PKG
    }
}

// ------- Stage B2 (r16/r19-validated): per-(b,c) key-build + prune + exact rescore +
//         rank-select + lazy box decode + trimmed bitmask NMS -------
__global__ __launch_bounds__(256) void tail_kernel(
        const float* __restrict__ p0, const float* __restrict__ p1,
        const float* __restrict__ p2,
        const float* __restrict__ so_arr,
        const unsigned long long* __restrict__ glist,
        const unsigned int* __restrict__ gcnt,
        DecParams dp,
        float* __restrict__ out) {
    __shared__ unsigned int kbuf[GCAP];            // 8 KB approx keys
    unsigned long long* skeyF = (unsigned long long*)kbuf;  // fallback alias [1024]
    __shared__ unsigned long long skeyM[PRUNECAP]; // 4 KB main rescore keys
    __shared__ unsigned long long sorted[TOPK];
    __shared__ unsigned long long mskp[2 * TOPK];
    __shared__ float4 bxs4[TOPK];
    __shared__ float pvs[TOPK];
    __shared__ unsigned int hist[512];
    __shared__ unsigned int wtot[4];
    __shared__ unsigned long long aliveLDS[2];
    __shared__ unsigned int sh_bin, sh_above, gcount;

    int t = threadIdx.x;
    int w = t >> 6, lane = t & 63;
    int bid = blockIdx.x;          // b*80 + c
    int b = bid / NCLS;
    int c = bid % NCLS;

    for (int i = t; i < 512; i += 256) hist[i] = 0;
    if (t == 0) gcount = 0;
    __syncthreads();

    unsigned gcv = gcnt[bid];
    unsigned G = gcv < GCAP ? gcv : GCAP;
    bool fb = (gcv > GCAP) || (G < TOPK);
    const unsigned long long* gl = glist + (size_t)bid * GCAP;

    // wave-shfl suffix scan over 256 threads (suffix-inclusive); 2 barriers total
    auto suffixScan = [&](unsigned mt, unsigned& total) -> unsigned {
        __syncthreads();
        unsigned sfx = mt;
#pragma unroll
        for (int d = 1; d < 64; d <<= 1) {
            unsigned o = (unsigned)__shfl_down((int)sfx, d);
            if (lane + d < 64) sfx += o;
        }
        if (lane == 0) wtot[w] = sfx;
        __syncthreads();
        unsigned cross = 0;
#pragma unroll
        for (int ww = 0; ww < 4; ++ww) if (ww > w) cross += wtot[ww];
        total = wtot[0] + wtot[1] + wtot[2] + wtot[3];
        return sfx + cross;
    };

    auto rankSelect2 = [&](const unsigned long long* sk, unsigned Gc) {
        if (t < TOPK) sorted[t] = 0ULL;
        __syncthreads();
        if ((unsigned)t < Gc) {
            unsigned long long o0 = sk[t];
            bool v1 = (unsigned)(t + 256) < Gc;
            unsigned long long o1 = v1 ? sk[t + 256] : 0ULL;
            unsigned r0 = 0, r1 = 0;
            for (unsigned j = 0; j < Gc; ++j) {
                unsigned long long kj = sk[j];    // wave-uniform addr -> LDS broadcast
                r0 += (kj > o0); r1 += (kj > o1);
            }
            if (r0 < TOPK) sorted[r0] = o0;
            if (v1 && r1 < TOPK) sorted[r1] = o1;
        }
        __syncthreads();
    };
    auto rankSelect4 = [&](const unsigned long long* sk, unsigned Gc) {
        if (t < TOPK) sorted[t] = 0ULL;
        __syncthreads();
        if ((unsigned)t < Gc) {
            unsigned i1 = t + 256, i2 = t + 512, i3 = t + 768;
            bool v1 = i1 < Gc, v2 = i2 < Gc, v3 = i3 < Gc;
            unsigned long long o0 = sk[t];
            unsigned long long o1 = v1 ? sk[i1] : 0ULL;
            unsigned long long o2 = v2 ? sk[i2] : 0ULL;
            unsigned long long o3 = v3 ? sk[i3] : 0ULL;
            unsigned r0 = 0, r1 = 0, r2 = 0, r3 = 0;
            for (unsigned j = 0; j < Gc; ++j) {
                unsigned long long kj = sk[j];
                r0 += (kj > o0); r1 += (kj > o1); r2 += (kj > o2); r3 += (kj > o3);
            }
            if (r0 < TOPK) sorted[r0] = o0;
            if (v1 && r1 < TOPK) sorted[r1] = o1;
            if (v2 && r2 < TOPK) sorted[r2] = o2;
            if (v3 && r3 < TOPK) sorted[r3] = o3;
        }
        __syncthreads();
    };

    // scattered x reload for one candidate index n (L2/L3-hot; r6-validated pattern)
    auto loadX = [&](unsigned n, unsigned a, unsigned r) -> float {
        size_t cb = (size_t)b * 255 + (size_t)a * 85 + 5 + (size_t)c;
        if (r < 5776u)      return p0[cb * 5776 + r];
        else if (r < 7220u) return p1[cb * 1444 + (r - 5776u)];
        else                return p2[cb * 361  + (r - 7220u)];
    };

    if (!fb) {
        // --- key-build + histogram from compact global list ---
        for (unsigned i = t; i < G; i += 256) {
            unsigned long long e = gl[i];
            float x = __uint_as_float((unsigned)(e >> 32));
            unsigned n = (unsigned)(e & 0xFFFFFFFFu);
            unsigned a = n / SUMHW;
            unsigned r = n - a * SUMHW;
            float so = so_arr[(size_t)b * PADNN + a * ASTRIDE + r];
            float st = 1.0f / (1.0f + __expf(-x));   // approx sigmoid, err few ulp
            unsigned key = __float_as_uint(st * so); // >= ~0.5999 > KB2 always
            kbuf[i] = key;
            unsigned bin = (key - KB2) >> 14;
            if (bin > 511u) bin = 511u;
            atomicAdd(&hist[bin], 1u);
        }
        __syncthreads();

        unsigned m0 = hist[2 * t], m1 = hist[2 * t + 1];
        unsigned total;
        unsigned si = suffixScan(m0 + m1, total);
        unsigned se = si - (m0 + m1);
        if (se < TOPK && TOPK <= si) {              // unique crossing thread
            if (TOPK <= se + m1) { sh_bin = 2 * t + 1; sh_above = se; }
            else                 { sh_bin = 2 * t;     sh_above = se + m1; }
        }
        __syncthreads();
        unsigned B1 = sh_bin, above1 = sh_above;
        unsigned cntB = hist[B1];
        unsigned binlo = KB2 + (B1 << 14);
        if (above1 + cntB > PRUNECAP - 64) {
            fb = true;                               // fat bin (~never): full re-scan
        } else {
            // --- pass 2: keep keys >= binlo - 256ulp (r3-validated margin);
            //             exact-rescore survivors only (reference-identical chain) ---
            unsigned gth = binlo - 256;
            for (unsigned i = t; i < G; i += 256) {
                if (kbuf[i] >= gth) {
                    unsigned pos = atomicAdd(&gcount, 1u);
                    if (pos < PRUNECAP) {
                        unsigned long long e = gl[i];
                        float x = __uint_as_float((unsigned)(e >> 32));
                        unsigned n = (unsigned)(e & 0xFFFFFFFFu);
                        unsigned a = n / SUMHW;
                        unsigned r = n - a * SUMHW;
                        float so = so_arr[(size_t)b * PADNN + a * ASTRIDE + r];
                        float ex = so * sigf(x);
                        skeyM[pos] = (ex > 0.3f)
                            ? (((unsigned long long)__float_as_uint(ex) << 32) |
                               (unsigned)(~n))
                            : (unsigned long long)(unsigned)(~n);   // unique dead key
                    }
                }
            }
            __syncthreads();
            if (gcount > PRUNECAP) fb = true;        // overflow (~never): full re-scan
            if (!fb) {
                unsigned Gc = gcount;
                rankSelect2(skeyM, Gc);
                // success <=> kept 128th has ex >= 0.6f (every scan-missed elem < 0.6f)
                bool ok = (Gc >= TOPK) && ((unsigned)(sorted[TOPK - 1] >> 32) >= SBITS);
                if (!ok) fb = true;
            }
        }
    }

    if (fb) {
        // ---- full re-scan fallback (r3/r4 validated); never taken on bench data ----
        auto scanScalar = [&](auto&& body) {
#pragma unroll
            for (int s = 0; s < 3; ++s) {
                const float* __restrict__ pr = (s == 0) ? p0 : (s == 1) ? p1 : p2;
                const int HW  = (s == 0) ? 5776 : (s == 1) ? 1444 : 361;
                const int OFF = (s == 0) ? 0 : (s == 1) ? 5776 : 7220;
#pragma unroll
                for (int a = 0; a < 3; ++a) {
                    const float* __restrict__ cp =
                        pr + ((size_t)b * 255 + (size_t)a * 85 + 5 + (size_t)c) * (size_t)HW;
                    const float* __restrict__ sop =
                        so_arr + (size_t)b * PADNN + a * ASTRIDE + OFF;
                    int n0 = a * SUMHW + OFF;
                    for (int i = t; i < HW; i += 256) {
                        float so = sop[i];
                        if (so <= 0.2999f) continue;
                        float x = cp[i];
                        float st = 1.0f / (1.0f + __expf(-x));
                        float sca = st * so;
                        if (sca > 0.2999f) body(sca, x, so, n0 + i);
                    }
                }
            }
        };
        __syncthreads();                 // kbuf reads done; skeyF may reuse it
        for (int i = t; i < 512; i += 256) hist[i] = 0;
        if (t == 0) gcount = 0;
        __syncthreads();
        scanScalar([&](float sca, float, float, int) {
            unsigned bin = (__float_as_uint(sca) - KEYBASE) >> 15;
            if (bin > 511u) bin = 511u;
            atomicAdd(&hist[bin], 1u);
        });
        __syncthreads();
        unsigned m0 = hist[2 * t], m1 = hist[2 * t + 1];
        unsigned total;
        unsigned si = suffixScan(m0 + m1, total);
        bool gatherAll = (total < TOPK);
        unsigned gth = 0;
        if (!gatherAll) {
            unsigned se = si - (m0 + m1);
            if (se < TOPK && TOPK <= si) {
                if (TOPK <= se + m1) { sh_bin = 2 * t + 1; sh_above = se; }
                else                 { sh_bin = 2 * t;     sh_above = se + m1; }
            }
            __syncthreads();
            unsigned B1 = sh_bin, above1 = sh_above;
            unsigned cntB = hist[B1];
            unsigned binlo = KEYBASE + (B1 << 15);
            __syncthreads();
            if (above1 + cntB <= 768) {
                gth = binlo - 256;
            } else {
                if (t < 256) hist[t] = 0;
                __syncthreads();
                scanScalar([&](float sca, float, float, int) {
                    unsigned key = __float_as_uint(sca);
                    if (((key - KEYBASE) >> 15) == B1) {
                        unsigned sub = (key - binlo) >> 7;
                        if (sub > 255u) sub = 255u;
                        atomicAdd(&hist[sub], 1u);
                    }
                });
                __syncthreads();
                unsigned R2 = TOPK - above1;
                unsigned sl = hist[t];
                unsigned tot2;
                unsigned si2 = suffixScan(sl, tot2);
                unsigned se2 = si2 - sl;
                if (se2 < R2 && R2 <= si2) sh_bin = (unsigned)t;
                __syncthreads();
                gth = binlo + (sh_bin << 7) - 256;
            }
        }
        __syncthreads();
        scanScalar([&](float sca, float x, float so, int n) {
            unsigned key = __float_as_uint(sca);
            if (gatherAll || key >= gth) {
                unsigned pos = atomicAdd(&gcount, 1u);
                if (pos < CAP) {
                    float ex = so * sigf(x);
                    skeyF[pos] = (ex > 0.3f)
                        ? (((unsigned long long)__float_as_uint(ex) << 32) |
                           (unsigned)(~(unsigned)n))
                        : (unsigned long long)(unsigned)(~(unsigned)n);
                }
            }
        });
        __syncthreads();
        unsigned Gc = gcount < CAP ? gcount : CAP;
        rankSelect4(skeyF, Gc);
    }

    // --- extract top-128 + LAZY box decode (reference-identical f32 chain) ---
    if (t < TOPK) {
        unsigned long long e = sorted[t];
        bool vld = (e != 0ULL);
        float sc = __uint_as_float((unsigned)(e >> 32));
        unsigned n = ~(unsigned)(e & 0xFFFFFFFFu);
        float4 bb = make_float4(0.f, 0.f, 0.f, 0.f);
        if (vld) {
            unsigned a = n / SUMHW;
            unsigned r = n - a * SUMHW;
            int s, S, HW, off; const float* pr;
            if (r < 5776u)      { s = 0; S = 76; HW = 5776; off = 0;    pr = p0; }
            else if (r < 7220u) { s = 1; S = 38; HW = 1444; off = 5776; pr = p1; }
            else                { s = 2; S = 19; HW = 361;  off = 7220; pr = p2; }
            int cell = (int)r - off;
            const float* pb = pr + ((size_t)b * 255 + (size_t)a * 85) * (size_t)HW + cell;
            float tx = pb[0];
            float ty = pb[(size_t)HW];
            float tw = pb[(size_t)2 * HW];
            float th = pb[(size_t)3 * HW];
            float Sf = (float)S;
            float gx = (float)(cell % S);
            float gy = (float)(cell / S);
            float cx = (sigf(tx) + gx) / Sf;
            float cy = (sigf(ty) + gy) / Sf;
            float aw = dp.aw[s * 3 + a], ah = dp.ah[s * 3 + a];
            float bw = expf_cr(tw) * aw;
            float bh = expf_cr(th) * ah;
            float x1 = cx - 0.5f * bw;
            float y1 = cy - 0.5f * bh;
            bb = make_float4(x1, y1, x1 + bw, y1 + bh);
        }
        bxs4[t] = bb;
        pvs[t] = vld ? sc : -1.0f;    // dead-unique key -> sc = 0.0 (never kept/suppresses)
    }
    __syncthreads();

    // --- bitmask NMS: trimmed parallel IoU mask build, then wave-0 bitmask greedy ---
    {
        int i = t >> 1, h = t & 1;
        unsigned long long m = 0;
        if (!(h == 0 && i >= 64)) {                  // mskp[i>=64][0] never read
            float4 bi = bxs4[i];
            float ai = (bi.z - bi.x) * (bi.w - bi.y);
            int jb = h << 6;
            int kstart = (h == 0) ? (i + 1) : ((i >= 64) ? (i - 63) : 0);
            for (int k = kstart; k < 64; ++k) {
                int j = jb + k;
                float4 bj = bxs4[j];
                float aj = (bj.z - bj.x) * (bj.w - bj.y);
                float xx1 = fmaxf(bi.x, bj.x), yy1 = fmaxf(bi.y, bj.y);
                float xx2 = fminf(bi.z, bj.z), yy2 = fminf(bi.w, bj.w);
                float ww = fmaxf(xx2 - xx1, 0.0f), hh = fmaxf(yy2 - yy1, 0.0f);
                float inter = ww * hh;
                float iou = inter / (ai + aj - inter);
                if (j > i && iou > 0.45f) m |= (1ull << k);
            }
        }
        mskp[(i << 1) | h] = m;
    }
    __syncthreads();
    if (t < 64) {
        unsigned long long A0 = __ballot(pvs[t] > 0.0f);
        unsigned long long A1 = __ballot(pvs[t + 64] > 0.0f);
        for (int i = 0; i < 64; ++i) {
            if ((A0 >> i) & 1) { A0 &= ~mskp[i << 1]; A1 &= ~mskp[(i << 1) | 1]; }
        }
        for (int i = 0; i < 64; ++i) {
            if ((A1 >> i) & 1) { A1 &= ~mskp[((64 + i) << 1) | 1]; }
        }
        if (t == 0) { aliveLDS[0] = A0; aliveLDS[1] = A1; }
    }
    __syncthreads();

    // --- write [K,6] = x1,y1,x2,y2,score,class ---
    unsigned long long A0 = aliveLDS[0], A1 = aliveLDS[1];
    float* o = out + (size_t)bid * TOPK * 6;
    for (int i = t; i < TOPK; i += 256) {
        bool alive = (i < 64) ? ((A0 >> i) & 1) : ((A1 >> (i - 64)) & 1);
        float p = pvs[i];
        bool kept = alive && (p > 0.0f);
        float4 bb = bxs4[i];
        o[i * 6 + 0] = kept ? bb.x : 0.0f;
        o[i * 6 + 1] = kept ? bb.y : 0.0f;
        o[i * 6 + 2] = kept ? bb.z : 0.0f;
        o[i * 6 + 3] = kept ? bb.w : 0.0f;
        o[i * 6 + 4] = kept ? p : 0.0f;
        o[i * 6 + 5] = (float)c;
    }
}

extern "C" void kernel_launch(void* const* d_in, const int* in_sizes, int n_in,
                              void* d_out, int out_size, void* d_ws, size_t ws_size,
                              hipStream_t stream) {
    const float* p0 = (const float*)d_in[0];
    const float* p1 = (const float*)d_in[1];
    const float* p2 = (const float*)d_in[2];
    float* out = (float*)d_out;

    char* ws = (char*)d_ws;
    float* so_arr = (float*)ws;                              // 1,456,128 B
    float* xthr   = (float*)(ws + 1456128ull);               // 1,456,128 B
    unsigned int* gcnt = (unsigned int*)(ws + 2912256ull);   // 5,120 B
    unsigned long long* glist = (unsigned long long*)(ws + 2920448ull); // 20,971,520 B

    static const float ANC[3][3][2] = {
        {{12, 16}, {19, 36}, {40, 28}},
        {{36, 75}, {76, 55}, {72, 146}},
        {{142, 110}, {192, 243}, {459, 401}},
    };
    static const int RED[3] = {8, 16, 32};
    static const int SS[3]  = {76, 38, 19};

    DecParams dp;
    for (int s = 0; s < 3; ++s)
        for (int a = 0; a < 3; ++a) {
            float Sf = (float)SS[s];
            dp.aw[s * 3 + a] = (ANC[s][a][0] / (float)RED[s]) / Sf;  // same f32 chain as ref
            dp.ah[s * 3 + a] = (ANC[s][a][1] / (float)RED[s]) / Sf;
        }

    hipMemsetAsync(gcnt, 0, BATCH * NCLS * sizeof(unsigned int), stream);
    decode_kernel<<<BATCH * 27, 256, 0, stream>>>(p0, p1, p2, so_arr, xthr);
    flat_scan_kernel<<<(TOTW + 255) / 256, 256, 0, stream>>>(p0, p1, p2, xthr,
                                                             glist, gcnt);
    tail_kernel<<<BATCH * NCLS, 256, 0, stream>>>(p0, p1, p2, so_arr,
                                                  glist, gcnt, dp, out);
}

// Round 21
// 67.356 us; speedup vs baseline: 13.6130x; 13.6130x over previous
//
#include <hip/hip_runtime.h>
#include <math.h>
#include <stdint.h>

#define BATCH 16
#define NCLS 80
#define SUMHW 7581            // 76*76 + 38*38 + 19*19
#define NN 22743              // 3 anchors * SUMHW
#define ASTRIDE 7584          // padded per-anchor stride for so/xthr (7581 -> 7584, /4)
#define PADNN (3 * ASTRIDE)   // 22752
#define TOPK 128
#define CAP 1024              // fallback gather cap
#define WCAP 320              // per-wave capture cap (mean ~170/wave, +11 sigma)
#define GMAX (4 * WCAP)       // 1280
#define PRUNECAP 512          // post-prune survivor cap
#define KEYBASE 0x3E800000u   // bits of 0.25f (fallback histogram base)
#define KB2     0x3F180000u   // bits of 0.59375f (prune histogram base)
#define SBITS   0x3F19999Au   // bits of 0.6f

typedef float f32x4 __attribute__((ext_vector_type(4)));

// exact sigmoid matching numpy f32 chain: correctly-rounded exp (double) -> f32 ops
__device__ __forceinline__ float sigf(float x) {
    float e = (float)exp(-(double)x);
    return 1.0f / (1.0f + e);
}
__device__ __forceinline__ float expf_cr(float x) {
    return (float)exp((double)x);
}

struct DecParams { float aw[9]; float ah[9]; };

// ---------------- Stage A: exact objectness + x-threshold (obj channel only, float4) ----
// xthr correctness (r5-r19 validated):
//   Tp = 0.59999 (< 0.6f).  thr = -log(so/Tp - 1)  =>  sigmoid(thr) = Tp/so.
//   ex >= 0.6f  =>  x > thr (captured).   x <= thr  =>  ex < 0.6f (safe to miss).
//   so <= 0.59999f  =>  ex < 0.6f  =>  xthr=+INF.
__global__ __launch_bounds__(256) void decode_kernel(
        const float* __restrict__ p0, const float* __restrict__ p1,
        const float* __restrict__ p2,
        float* __restrict__ so_arr, float* __restrict__ xthr_arr) {
    int blk = blockIdx.x;              // 16 b * 3 a * 9 segs = 432
    int b = blk / 27;
    int rem = blk % 27;
    int a = rem / 9;
    int seg = rem % 9;
    int s, segi;
    if (seg < 6)      { s = 0; segi = seg; }
    else if (seg < 8) { s = 1; segi = seg - 6; }
    else              { s = 2; segi = 0; }
    const int HW_[3]  = {5776, 1444, 361};
    const int OFF_[3] = {0, 5776, 7220};
    const float* __restrict__ pr = (s == 0) ? p0 : (s == 1) ? p1 : p2;
    int HW = HW_[s], OFF = OFF_[s];
    int t = threadIdx.x;

    auto mkthr = [](float so) {
        float thr = __int_as_float(0x7F800000);       // +INF
        if (so > 0.59999f) {
            double arg = (double)so / 0.59999 - 1.0;
            thr = __double2float_rd(-log(arg));       // round DOWN: conservative capture
        }
        return thr;
    };

    if (s != 2) {
        int cell0 = segi * 1024 + t * 4;
        if (cell0 >= HW) return;                      // active threads are full float4s
        const float4* ob4 =
            (const float4*)(pr + ((size_t)b * 255 + (size_t)a * 85 + 4) * (size_t)HW);
        float4 ov = ob4[cell0 >> 2];
        float4 sov, thv;
        sov.x = sigf(ov.x); thv.x = mkthr(sov.x);
        sov.y = sigf(ov.y); thv.y = mkthr(sov.y);
        sov.z = sigf(ov.z); thv.z = mkthr(sov.z);
        sov.w = sigf(ov.w); thv.w = mkthr(sov.w);
        size_t pidx = (size_t)b * PADNN + a * ASTRIDE + OFF + cell0;
        *(float4*)(so_arr + pidx)   = sov;
        *(float4*)(xthr_arr + pidx) = thv;
    } else {
        const float* ob = pr + ((size_t)b * 255 + (size_t)a * 85 + 4) * 361;
        for (int i = t; i < 361; i += 256) {
            float so = sigf(ob[i]);
            size_t pidx = (size_t)b * PADNN + a * ASTRIDE + 7220 + i;
            so_arr[pidx] = so;
            xthr_arr[pidx] = mkthr(so);
        }
    }
}

// ------- Stage B (fused): pair-batched asm compare-scan capturing (x,n) +
//         batched-atomic push + fused key+hist + prune + exact rescore +
//         rank-select + lazy box decode + bitmask NMS. No global intermediates. -------
__global__ __launch_bounds__(256) void select_nms_kernel(
        const float* __restrict__ p0, const float* __restrict__ p1,
        const float* __restrict__ p2,
        const float* __restrict__ so_arr,
        const float* __restrict__ xthr_arr,
        DecParams dp,
        float* __restrict__ out) {
    // wn64 (scan capture) is dead before the fallback gather; skeyF aliases it.
    __shared__ __attribute__((aligned(16))) unsigned long long wn64[4 * WCAP]; // 10240 B
    unsigned long long* skeyF = wn64;            // fallback keys [1024] (8192 B alias)
    __shared__ unsigned int kbuf[GMAX];          // 5120 B approx keys (compacted)
    __shared__ unsigned long long skeyM[PRUNECAP]; // 4096 B main rescore keys
    __shared__ unsigned long long sorted[TOPK];  // 1024 B
    __shared__ unsigned long long mskp[2 * TOPK];// 2048 B
    __shared__ float4 bxs4[TOPK];                // 2048 B
    __shared__ float pvs[TOPK];                  // 512 B
    __shared__ unsigned int hist[512];           // 2048 B
    __shared__ unsigned int sums[256];           // 1024 B
    __shared__ unsigned int wvc[4];
    __shared__ unsigned long long aliveLDS[2];
    __shared__ unsigned int sh_bin, sh_above, gcount;

    int t = threadIdx.x;
    int w = t >> 6, lane = t & 63;
    int bid = blockIdx.x;          // b*80 + c
    int b = bid / NCLS;
    int c = bid % NCLS;

    if (t < 4) wvc[t] = 0;
    for (int i = t; i < 512; i += 256) hist[i] = 0;
    __syncthreads();

    // batched push: ONE atomic per lane per group, then static conditional writes
    auto cmpPushB = [&](f32x4 A0, f32x4 A1, f32x4 A2,
                        f32x4 Q0, f32x4 Q1, f32x4 Q2, int cellb) {
        unsigned m = 0;
        m |= (A0.x > Q0.x) ? 0x001u : 0u;  m |= (A0.y > Q0.y) ? 0x002u : 0u;
        m |= (A0.z > Q0.z) ? 0x004u : 0u;  m |= (A0.w > Q0.w) ? 0x008u : 0u;
        m |= (A1.x > Q1.x) ? 0x010u : 0u;  m |= (A1.y > Q1.y) ? 0x020u : 0u;
        m |= (A1.z > Q1.z) ? 0x040u : 0u;  m |= (A1.w > Q1.w) ? 0x080u : 0u;
        m |= (A2.x > Q2.x) ? 0x100u : 0u;  m |= (A2.y > Q2.y) ? 0x200u : 0u;
        m |= (A2.z > Q2.z) ? 0x400u : 0u;  m |= (A2.w > Q2.w) ? 0x800u : 0u;
        if (m) {
            unsigned pos = atomicAdd(&wvc[w], (unsigned)__popc(m));
            unsigned long long* wl = wn64 + w * WCAP;
#define PKW(bit, val, nn) \
            if (m & (bit)) { if (pos < WCAP) wl[pos] = \
                (((unsigned long long)__float_as_uint(val)) << 32) | (unsigned)(nn); \
                pos++; }
            PKW(0x001u, A0.x, cellb + 0)
            PKW(0x002u, A0.y, cellb + 1)
            PKW(0x004u, A0.z, cellb + 2)
            PKW(0x008u, A0.w, cellb + 3)
            PKW(0x010u, A1.x, SUMHW + cellb + 0)
            PKW(0x020u, A1.y, SUMHW + cellb + 1)
            PKW(0x040u, A1.z, SUMHW + cellb + 2)
            PKW(0x080u, A1.w, SUMHW + cellb + 3)
            PKW(0x100u, A2.x, 2 * SUMHW + cellb + 0)
            PKW(0x200u, A2.y, 2 * SUMHW + cellb + 1)
            PKW(0x400u, A2.z, 2 * SUMHW + cellb + 2)
            PKW(0x800u, A2.w, 2 * SUMHW + cellb + 3)
#undef PKW
        }
    };

    // --- pair-batched asm scan: 12 loads + vmcnt(0) in ONE asm block (nothing pending
    //     escapes an asm block — r12 crash lesson). 12KB/wave per drain window. ---
    auto scanBlock = [&](const float* __restrict__ pr, int HW, int OFF) {
        const int nq = HW >> 2;
        unsigned long long bx0 = (unsigned long long)(uintptr_t)
            (pr + ((size_t)b * 255 + 0 * 85 + 5 + (size_t)c) * (size_t)HW);
        unsigned long long bx1 = (unsigned long long)(uintptr_t)
            (pr + ((size_t)b * 255 + 1 * 85 + 5 + (size_t)c) * (size_t)HW);
        unsigned long long bx2 = (unsigned long long)(uintptr_t)
            (pr + ((size_t)b * 255 + 2 * 85 + 5 + (size_t)c) * (size_t)HW);
        unsigned long long bq0 = (unsigned long long)(uintptr_t)
            (xthr_arr + (size_t)b * PADNN + 0 * ASTRIDE + OFF);
        unsigned long long bq1 = (unsigned long long)(uintptr_t)
            (xthr_arr + (size_t)b * PADNN + 1 * ASTRIDE + OFF);
        unsigned long long bq2 = (unsigned long long)(uintptr_t)
            (xthr_arr + (size_t)b * PADNN + 2 * ASTRIDE + OFF);
        int i = t;
        for (; i + 256 < nq; i += 512) {
            unsigned vo1 = (unsigned)i << 4;
            unsigned vo2 = (unsigned)(i + 256) << 4;
            f32x4 x0, x1, x2, x3, x4, x5, q0, q1, q2, q3, q4, q5;
            asm volatile(
                "global_load_dwordx4 %0, %12, %14\n\t"
                "global_load_dwordx4 %1, %12, %15\n\t"
                "global_load_dwordx4 %2, %12, %16\n\t"
                "global_load_dwordx4 %3, %13, %14\n\t"
                "global_load_dwordx4 %4, %13, %15\n\t"
                "global_load_dwordx4 %5, %13, %16\n\t"
                "global_load_dwordx4 %6, %12, %17\n\t"
                "global_load_dwordx4 %7, %12, %18\n\t"
                "global_load_dwordx4 %8, %12, %19\n\t"
                "global_load_dwordx4 %9, %13, %17\n\t"
                "global_load_dwordx4 %10, %13, %18\n\t"
                "global_load_dwordx4 %11, %13, %19\n\t"
                "s_waitcnt vmcnt(0)"
                : "=&v"(x0), "=&v"(x1), "=&v"(x2), "=&v"(x3), "=&v"(x4), "=&v"(x5),
                  "=&v"(q0), "=&v"(q1), "=&v"(q2), "=&v"(q3), "=&v"(q4), "=&v"(q5)
                : "v"(vo1), "v"(vo2), "s"(bx0), "s"(bx1), "s"(bx2),
                  "s"(bq0), "s"(bq1), "s"(bq2));
            cmpPushB(x0, x1, x2, q0, q1, q2, OFF + 4 * i);
            cmpPushB(x3, x4, x5, q3, q4, q5, OFF + 4 * (i + 256));
        }
        if (i < nq) {
            unsigned voff = (unsigned)i << 4;
            f32x4 x0, x1, x2, q0, q1, q2;
            asm volatile(
                "global_load_dwordx4 %0, %6, %7\n\t"
                "global_load_dwordx4 %1, %6, %8\n\t"
                "global_load_dwordx4 %2, %6, %9\n\t"
                "global_load_dwordx4 %3, %6, %10\n\t"
                "global_load_dwordx4 %4, %6, %11\n\t"
                "global_load_dwordx4 %5, %6, %12\n\t"
                "s_waitcnt vmcnt(0)"
                : "=&v"(x0), "=&v"(x1), "=&v"(x2),
                  "=&v"(q0), "=&v"(q1), "=&v"(q2)
                : "v"(voff), "s"(bx0), "s"(bx1), "s"(bx2),
                  "s"(bq0), "s"(bq1), "s"(bq2));
            cmpPushB(x0, x1, x2, q0, q1, q2, OFF + 4 * i);
        }
    };
    scanBlock(p0, 5776, 0);
    scanBlock(p1, 1444, 5776);
#pragma unroll
    for (int a = 0; a < 3; ++a) {               // s2: 361 cells, scalar
        const float* __restrict__ cp =
            p2 + ((size_t)b * 255 + (size_t)a * 85 + 5 + (size_t)c) * 361;
        const float* __restrict__ xt = xthr_arr + (size_t)b * PADNN + a * ASTRIDE + 7220;
        int n0 = a * SUMHW + 7220;
        for (int i = t; i < 361; i += 256) {
            float xv = cp[i];
            if (xv > xt[i]) {
                unsigned pos = atomicAdd(&wvc[w], 1u);
                if (pos < WCAP) wn64[w * WCAP + pos] =
                    (((unsigned long long)__float_as_uint(xv)) << 32) | (unsigned)(n0 + i);
            }
        }
    }
    __syncthreads();

    unsigned cw0 = wvc[0], cw1 = wvc[1], cw2 = wvc[2], cw3 = wvc[3];
    bool ovf = (cw0 > WCAP) || (cw1 > WCAP) || (cw2 > WCAP) || (cw3 > WCAP);
    unsigned G = cw0 + cw1 + cw2 + cw3;          // valid only if !ovf (<= GMAX)
    bool fb = ovf || (G < TOPK);   // <TOPK: true top-128 needs sub-0.6 elems never captured

    // all-pairs rank selection: keys unique (low bits carry ~n) => rank is a permutation
    auto rankSelect = [&](const unsigned long long* sk, unsigned Gc) {
        if (t < TOPK) sorted[t] = 0ULL;
        __syncthreads();
        unsigned i0 = t, i1 = t + 256, i2 = t + 512, i3 = t + 768;
        bool v0 = i0 < Gc, v1 = i1 < Gc, v2 = i2 < Gc, v3 = i3 < Gc;
        unsigned long long o0 = v0 ? sk[i0] : 0ULL;
        unsigned long long o1 = v1 ? sk[i1] : 0ULL;
        unsigned long long o2 = v2 ? sk[i2] : 0ULL;
        unsigned long long o3 = v3 ? sk[i3] : 0ULL;
        unsigned r0 = 0, r1 = 0, r2 = 0, r3 = 0;
        for (unsigned j = 0; j < Gc; ++j) {
            unsigned long long kj = sk[j];        // wave-uniform addr -> LDS broadcast
            r0 += (kj > o0); r1 += (kj > o1); r2 += (kj > o2); r3 += (kj > o3);
        }
        if (v0 && r0 < TOPK) sorted[r0] = o0;
        if (v1 && r1 < TOPK) sorted[r1] = o1;
        if (v2 && r2 < TOPK) sorted[r2] = o2;
        if (v3 && r3 < TOPK) sorted[r3] = o3;
        __syncthreads();
    };

    if (!fb) {
        // --- key-build + histogram FUSED; x read from LDS (no global reloads) ---
        unsigned woff = 0;
        if (w > 0) woff += cw0;
        if (w > 1) woff += cw1;
        if (w > 2) woff += cw2;
        unsigned mycnt = (w == 0) ? cw0 : (w == 1) ? cw1 : (w == 2) ? cw2 : cw3;
        for (unsigned i = lane; i < mycnt; i += 64) {
            unsigned long long e = wn64[w * WCAP + i];
            float x = __uint_as_float((unsigned)(e >> 32));
            unsigned n = (unsigned)(e & 0xFFFFFFFFu);
            unsigned a = n / SUMHW;
            unsigned r = n - a * SUMHW;
            float so = so_arr[(size_t)b * PADNN + a * ASTRIDE + r];
            float st = 1.0f / (1.0f + __expf(-x));   // approx sigmoid, err few ulp
            unsigned key = __float_as_uint(st * so); // >= ~0.5999 > KB2 always
            kbuf[woff + i] = key;
            unsigned bin = (key - KB2) >> 14;
            if (bin > 511u) bin = 511u;
            atomicAdd(&hist[bin], 1u);
        }
        if (t == 0) gcount = 0;
        __syncthreads();

        // --- suffix block-scan (r9-r14 proven sums machinery) ---
        unsigned m0 = hist[2 * t], m1 = hist[2 * t + 1];
        sums[t] = m0 + m1;
        __syncthreads();
        for (int d = 1; d < 256; d <<= 1) {
            unsigned v = sums[t];
            if (t + d < 256) v += sums[t + d];
            __syncthreads();
            sums[t] = v;
            __syncthreads();
        }
        unsigned si = sums[t], se = si - (m0 + m1);
        if (se < TOPK && TOPK <= si) {              // unique crossing thread
            if (TOPK <= se + m1) { sh_bin = 2 * t + 1; sh_above = se; }
            else                 { sh_bin = 2 * t;     sh_above = se + m1; }
        }
        __syncthreads();
        unsigned B1 = sh_bin, above1 = sh_above;
        unsigned cntB = hist[B1];
        unsigned binlo = KB2 + (B1 << 14);
        if (above1 + cntB > PRUNECAP - 64) {
            fb = true;                               // fat bin (~never): full re-scan
        } else {
            // --- pass 2: keep keys >= binlo - 256ulp (r3-validated margin);
            //             exact-rescore survivors only (reference-identical chain) ---
            unsigned gth = binlo - 256;
            unsigned b1e = cw0, b2e = cw0 + cw1, b3e = b2e + cw2;
            for (unsigned i = t; i < G; i += 256) {
                if (kbuf[i] >= gth) {
                    unsigned pos = atomicAdd(&gcount, 1u);
                    if (pos < PRUNECAP) {
                        unsigned w2, off2;
                        if (i < b1e)      { w2 = 0; off2 = i; }
                        else if (i < b2e) { w2 = 1; off2 = i - b1e; }
                        else if (i < b3e) { w2 = 2; off2 = i - b2e; }
                        else              { w2 = 3; off2 = i - b3e; }
                        unsigned long long e = wn64[w2 * WCAP + off2];
                        float x = __uint_as_float((unsigned)(e >> 32));
                        unsigned n = (unsigned)(e & 0xFFFFFFFFu);
                        unsigned a = n / SUMHW;
                        unsigned r = n - a * SUMHW;
                        float so = so_arr[(size_t)b * PADNN + a * ASTRIDE + r];
                        float ex = so * sigf(x);
                        skeyM[pos] = (ex > 0.3f)
                            ? (((unsigned long long)__float_as_uint(ex) << 32) |
                               (unsigned)(~n))
                            : (unsigned long long)(unsigned)(~n);   // unique dead key
                    }
                }
            }
            __syncthreads();
            if (gcount > PRUNECAP) fb = true;        // overflow (~never): full re-scan
            if (!fb) {
                unsigned Gc = gcount;
                rankSelect(skeyM, Gc);
                // success <=> kept 128th has ex >= 0.6f (every scan-missed elem < 0.6f)
                bool ok = (Gc >= TOPK) && ((unsigned)(sorted[TOPK - 1] >> 32) >= SBITS);
                if (!ok) fb = true;
            }
        }
    }

    if (fb) {
        // ---- full re-scan fallback (r3/r4 validated); never taken on bench data ----
        auto scanScalar = [&](auto&& body) {
#pragma unroll
            for (int s = 0; s < 3; ++s) {
                const float* __restrict__ pr = (s == 0) ? p0 : (s == 1) ? p1 : p2;
                const int HW  = (s == 0) ? 5776 : (s == 1) ? 1444 : 361;
                const int OFF = (s == 0) ? 0 : (s == 1) ? 5776 : 7220;
#pragma unroll
                for (int a = 0; a < 3; ++a) {
                    const float* __restrict__ cp =
                        pr + ((size_t)b * 255 + (size_t)a * 85 + 5 + (size_t)c) * (size_t)HW;
                    const float* __restrict__ sop =
                        so_arr + (size_t)b * PADNN + a * ASTRIDE + OFF;
                    int n0 = a * SUMHW + OFF;
                    for (int i = t; i < HW; i += 256) {
                        float so = sop[i];
                        if (so <= 0.2999f) continue;
                        float x = cp[i];
                        float st = 1.0f / (1.0f + __expf(-x));
                        float sca = st * so;
                        if (sca > 0.2999f) body(sca, x, so, n0 + i);
                    }
                }
            }
        };
        __syncthreads();                 // wn64 reads done; skeyF may reuse it
        for (int i = t; i < 512; i += 256) hist[i] = 0;
        if (t == 0) gcount = 0;
        __syncthreads();
        scanScalar([&](float sca, float, float, int) {
            unsigned bin = (__float_as_uint(sca) - KEYBASE) >> 15;
            if (bin > 511u) bin = 511u;
            atomicAdd(&hist[bin], 1u);
        });
        __syncthreads();
        unsigned m0 = hist[2 * t], m1 = hist[2 * t + 1];
        sums[t] = m0 + m1;
        __syncthreads();
        for (int d = 1; d < 256; d <<= 1) {
            unsigned v = sums[t];
            if (t + d < 256) v += sums[t + d];
            __syncthreads();
            sums[t] = v;
            __syncthreads();
        }
        unsigned total = sums[0];
        bool gatherAll = (total < TOPK);
        unsigned gth = 0;
        if (!gatherAll) {
            unsigned si = sums[t], se = si - (m0 + m1);
            if (se < TOPK && TOPK <= si) {
                if (TOPK <= se + m1) { sh_bin = 2 * t + 1; sh_above = se; }
                else                 { sh_bin = 2 * t;     sh_above = se + m1; }
            }
            __syncthreads();
            unsigned B1 = sh_bin, above1 = sh_above;
            unsigned cntB = hist[B1];
            unsigned binlo = KEYBASE + (B1 << 15);
            __syncthreads();
            if (above1 + cntB <= 768) {
                gth = binlo - 256;
            } else {
                if (t < 256) hist[t] = 0;
                __syncthreads();
                scanScalar([&](float sca, float, float, int) {
                    unsigned key = __float_as_uint(sca);
                    if (((key - KEYBASE) >> 15) == B1) {
                        unsigned sub = (key - binlo) >> 7;
                        if (sub > 255u) sub = 255u;
                        atomicAdd(&hist[sub], 1u);
                    }
                });
                __syncthreads();
                unsigned R2 = TOPK - above1;
                unsigned sl = hist[t];
                sums[t] = sl;
                __syncthreads();
                for (int d = 1; d < 256; d <<= 1) {
                    unsigned v = sums[t];
                    if (t + d < 256) v += sums[t + d];
                    __syncthreads();
                    sums[t] = v;
                    __syncthreads();
                }
                unsigned si2 = sums[t], se2 = si2 - sl;
                if (se2 < R2 && R2 <= si2) sh_bin = (unsigned)t;
                __syncthreads();
                gth = binlo + (sh_bin << 7) - 256;
            }
        }
        __syncthreads();
        scanScalar([&](float sca, float x, float so, int n) {
            unsigned key = __float_as_uint(sca);
            if (gatherAll || key >= gth) {
                unsigned pos = atomicAdd(&gcount, 1u);
                if (pos < CAP) {
                    float ex = so * sigf(x);
                    skeyF[pos] = (ex > 0.3f)
                        ? (((unsigned long long)__float_as_uint(ex) << 32) |
                           (unsigned)(~(unsigned)n))
                        : (unsigned long long)(unsigned)(~(unsigned)n);
                }
            }
        });
        __syncthreads();
        unsigned Gc = gcount < CAP ? gcount : CAP;
        rankSelect(skeyF, Gc);
    }

    // --- extract top-128 + LAZY box decode (reference-identical f32 chain) ---
    if (t < TOPK) {
        unsigned long long e = sorted[t];
        bool vld = (e != 0ULL);
        float sc = __uint_as_float((unsigned)(e >> 32));
        unsigned n = ~(unsigned)(e & 0xFFFFFFFFu);
        float4 bb = make_float4(0.f, 0.f, 0.f, 0.f);
        if (vld) {
            unsigned a = n / SUMHW;
            unsigned r = n - a * SUMHW;
            int s, S, HW, off; const float* pr;
            if (r < 5776u)      { s = 0; S = 76; HW = 5776; off = 0;    pr = p0; }
            else if (r < 7220u) { s = 1; S = 38; HW = 1444; off = 5776; pr = p1; }
            else                { s = 2; S = 19; HW = 361;  off = 7220; pr = p2; }
            int cell = (int)r - off;
            const float* pb = pr + ((size_t)b * 255 + (size_t)a * 85) * (size_t)HW + cell;
            float tx = pb[0];
            float ty = pb[(size_t)HW];
            float tw = pb[(size_t)2 * HW];
            float th = pb[(size_t)3 * HW];
            float Sf = (float)S;
            float gx = (float)(cell % S);
            float gy = (float)(cell / S);
            float cx = (sigf(tx) + gx) / Sf;
            float cy = (sigf(ty) + gy) / Sf;
            float aw = dp.aw[s * 3 + a], ah = dp.ah[s * 3 + a];
            float bw = expf_cr(tw) * aw;
            float bh = expf_cr(th) * ah;
            float x1 = cx - 0.5f * bw;
            float y1 = cy - 0.5f * bh;
            bb = make_float4(x1, y1, x1 + bw, y1 + bh);
        }
        bxs4[t] = bb;
        pvs[t] = vld ? sc : -1.0f;    // dead-unique key -> sc = 0.0 (never kept/suppresses)
    }
    __syncthreads();

    // --- bitmask NMS: parallel IoU mask build, then wave-0 bitmask greedy ---
    {
        int i = t >> 1, h = t & 1;
        float4 bi = bxs4[i];
        float ai = (bi.z - bi.x) * (bi.w - bi.y);
        unsigned long long m = 0;
        int jb = h << 6;
        for (int k = 0; k < 64; ++k) {
            int j = jb + k;
            float4 bj = bxs4[j];
            float aj = (bj.z - bj.x) * (bj.w - bj.y);
            float xx1 = fmaxf(bi.x, bj.x), yy1 = fmaxf(bi.y, bj.y);
            float xx2 = fminf(bi.z, bj.z), yy2 = fminf(bi.w, bj.w);
            float ww = fmaxf(xx2 - xx1, 0.0f), hh = fmaxf(yy2 - yy1, 0.0f);
            float inter = ww * hh;
            float iou = inter / (ai + aj - inter);
            if (j > i && iou > 0.45f) m |= (1ull << k);
        }
        mskp[(i << 1) | h] = m;
    }
    __syncthreads();
    if (t < 64) {
        unsigned long long A0 = __ballot(pvs[t] > 0.0f);
        unsigned long long A1 = __ballot(pvs[t + 64] > 0.0f);
        for (int i = 0; i < 64; ++i) {
            if ((A0 >> i) & 1) { A0 &= ~mskp[i << 1]; A1 &= ~mskp[(i << 1) | 1]; }
        }
        for (int i = 0; i < 64; ++i) {
            if ((A1 >> i) & 1) { A1 &= ~mskp[((64 + i) << 1) | 1]; }  // lower half: j>i => 0
        }
        if (t == 0) { aliveLDS[0] = A0; aliveLDS[1] = A1; }
    }
    __syncthreads();

    // --- write [K,6] = x1,y1,x2,y2,score,class ---
    unsigned long long A0 = aliveLDS[0], A1 = aliveLDS[1];
    float* o = out + (size_t)bid * TOPK * 6;
    for (int i = t; i < TOPK; i += 256) {
        bool alive = (i < 64) ? ((A0 >> i) & 1) : ((A1 >> (i - 64)) & 1);
        float p = pvs[i];
        bool kept = alive && (p > 0.0f);
        float4 bb = bxs4[i];
        o[i * 6 + 0] = kept ? bb.x : 0.0f;
        o[i * 6 + 1] = kept ? bb.y : 0.0f;
        o[i * 6 + 2] = kept ? bb.z : 0.0f;
        o[i * 6 + 3] = kept ? bb.w : 0.0f;
        o[i * 6 + 4] = kept ? p : 0.0f;
        o[i * 6 + 5] = (float)c;
    }
}

extern "C" void kernel_launch(void* const* d_in, const int* in_sizes, int n_in,
                              void* d_out, int out_size, void* d_ws, size_t ws_size,
                              hipStream_t stream) {
    const float* p0 = (const float*)d_in[0];
    const float* p1 = (const float*)d_in[1];
    const float* p2 = (const float*)d_in[2];
    float* out = (float*)d_out;

    char* ws = (char*)d_ws;
    float* so_arr = (float*)ws;                    // 1,456,128 B
    float* xthr   = (float*)(ws + 1456128ull);     // 1,456,128 B

    static const float ANC[3][3][2] = {
        {{12, 16}, {19, 36}, {40, 28}},
        {{36, 75}, {76, 55}, {72, 146}},
        {{142, 110}, {192, 243}, {459, 401}},
    };
    static const int RED[3] = {8, 16, 32};
    static const int SS[3]  = {76, 38, 19};

    DecParams dp;
    for (int s = 0; s < 3; ++s)
        for (int a = 0; a < 3; ++a) {
            float Sf = (float)SS[s];
            dp.aw[s * 3 + a] = (ANC[s][a][0] / (float)RED[s]) / Sf;  // same f32 chain as ref
            dp.ah[s * 3 + a] = (ANC[s][a][1] / (float)RED[s]) / Sf;
        }

    decode_kernel<<<BATCH * 27, 256, 0, stream>>>(p0, p1, p2, so_arr, xthr);
    select_nms_kernel<<<BATCH * NCLS, 256, 0, stream>>>(p0, p1, p2, so_arr, xthr, dp, out);
}